// Round 1
// baseline (254.018 us; speedup 1.0000x reference)
//
#include <hip/hip_runtime.h>
#include <hip/hip_bf16.h>
#include <stdint.h>

#define SEQ 4096
#define DM  1024

typedef __attribute__((ext_vector_type(8))) short  s16x8;
typedef __attribute__((ext_vector_type(8))) _Float16 h16x8;
typedef __attribute__((ext_vector_type(4))) float  f32x4;

__device__ __forceinline__ ushort f2bf(float f) {
    union { float f; uint32_t u; } x; x.f = f;
    uint32_t r = x.u + 0x7fffu + ((x.u >> 16) & 1u);
    return (ushort)(r >> 16);
}

__device__ __forceinline__ void gload16(const void* g, void* l) {
    __builtin_amdgcn_global_load_lds(
        (const __attribute__((address_space(1))) void*)g,
        (__attribute__((address_space(3))) void*)l,
        16, 0, 0);
}

// ---------------------------------------------------------------------------
// fp32 -> bf16 convert (vectorized float4 -> 4x bf16)
// ---------------------------------------------------------------------------
__global__ __launch_bounds__(256) void cvt_bf16(const float* __restrict__ in,
                                                ushort* __restrict__ out, int n4) {
    int i = blockIdx.x * blockDim.x + threadIdx.x;
    if (i < n4) {
        float4 v = ((const float4*)in)[i];
        ushort4 o;
        o.x = f2bf(v.x); o.y = f2bf(v.y); o.z = f2bf(v.z); o.w = f2bf(v.w);
        ((ushort4*)out)[i] = o;
    }
}

// ---------------------------------------------------------------------------
// GEMM: C[M,N] = A[M,K] * B[N,K]^T  (both operands row-major with leading dim
// = K stride). 128x128 tile, BK=32, 4 waves, each wave 64x64 (4x4 frags of
// 16x16x32 bf16 MFMA). m97-style: global_load_lds width-16 staging.
// BIAS_MODE: 0 none, 1 bias[col], 2 bias[row].  OUT_MODE: 0 f32, 1 bf16, 2 f16
// ---------------------------------------------------------------------------
template<int BIAS_MODE, int OUT_MODE>
__global__ __launch_bounds__(256)
void gemm_bt(const ushort* __restrict__ A, int lda,
             const ushort* __restrict__ B, int ldb,
             const float* __restrict__ bias,
             void* __restrict__ Cout, int ldc,
             int K, float scale)
{
    constexpr int BK = 32;
    __shared__ alignas(16) ushort lsA[128 * BK];
    __shared__ alignas(16) ushort lsB[128 * BK];

    const int tid = threadIdx.x;
    const int w   = tid >> 6;
    const int l   = tid & 63;
    const int m0  = blockIdx.y * 128;
    const int n0  = blockIdx.x * 128;
    const int wm  = (w >> 1) * 64;   // wave row offset in tile
    const int wn  = (w & 1) * 64;    // wave col offset in tile

    // staging: each wave stages 16 rows per chunk, 2 chunks per matrix
    const int sr = l >> 2;           // row within 16-row chunk
    const int sc = (l & 3) * 8;      // col (elements)

    const ushort* gA0 = A + (size_t)(m0 + w * 16 + sr) * lda + sc;
    const ushort* gA1 = gA0 + (size_t)64 * lda;
    const ushort* gB0 = B + (size_t)(n0 + w * 16 + sr) * ldb + sc;
    const ushort* gB1 = gB0 + (size_t)64 * ldb;
    ushort* lA0 = &lsA[(w * 16) * BK];
    ushort* lA1 = &lsA[(64 + w * 16) * BK];
    ushort* lB0 = &lsB[(w * 16) * BK];
    ushort* lB1 = &lsB[(64 + w * 16) * BK];

    const int lr = l & 15;           // fragment row/col within 16
    const int kh = (l >> 4) * 8;     // fragment k offset

    f32x4 acc[4][4] = {};

    for (int k = 0; k < K; k += BK) {
        gload16(gA0 + k, lA0);
        gload16(gA1 + k, lA1);
        gload16(gB0 + k, lB0);
        gload16(gB1 + k, lB1);
        asm volatile("s_waitcnt vmcnt(0)" ::: "memory");
        __syncthreads();

        s16x8 af[4], bf[4];
#pragma unroll
        for (int i = 0; i < 4; ++i)
            af[i] = *(const s16x8*)&lsA[(wm + i * 16 + lr) * BK + kh];
#pragma unroll
        for (int j = 0; j < 4; ++j)
            bf[j] = *(const s16x8*)&lsB[(wn + j * 16 + lr) * BK + kh];
#pragma unroll
        for (int i = 0; i < 4; ++i)
#pragma unroll
            for (int j = 0; j < 4; ++j)
                acc[i][j] = __builtin_amdgcn_mfma_f32_16x16x32_bf16(af[i], bf[j], acc[i][j], 0, 0, 0);
        __syncthreads();
    }

    // epilogue: C/D layout col = lane&15, row = (lane>>4)*4 + r  (m91-verified)
    const int r0 = m0 + wm + ((l >> 4) << 2);
    const int c0 = n0 + wn + lr;
#pragma unroll
    for (int i = 0; i < 4; ++i) {
#pragma unroll
        for (int j = 0; j < 4; ++j) {
#pragma unroll
            for (int r = 0; r < 4; ++r) {
                const int row = r0 + i * 16 + r;
                const int col = c0 + j * 16;
                float v = acc[i][j][r];
                if (BIAS_MODE == 1) v += bias[col];
                if (BIAS_MODE == 2) v += bias[row];
                v *= scale;
                if (OUT_MODE == 0)      ((float*)Cout)[(size_t)row * ldc + col] = v;
                else if (OUT_MODE == 1) ((ushort*)Cout)[(size_t)row * ldc + col] = f2bf(v);
                else                    ((_Float16*)Cout)[(size_t)row * ldc + col] = (_Float16)v;
            }
        }
    }
}

// ---------------------------------------------------------------------------
// Row softmax: S (fp16, [4096][4096]) -> P (bf16) written IN-PLACE (each
// thread rewrites exactly the 16B chunks it read). fp32 math throughout.
// ---------------------------------------------------------------------------
__global__ __launch_bounds__(256) void softmax_rows(void* __restrict__ Sbase) {
    const int row = blockIdx.x;
    const int tid = threadIdx.x;
    const _Float16* srow = (const _Float16*)Sbase + (size_t)row * SEQ;

    float f[16];
#pragma unroll
    for (int j = 0; j < 2; ++j) {
        h16x8 v = *(const h16x8*)(srow + (size_t)(tid + j * 256) * 8);
#pragma unroll
        for (int e = 0; e < 8; ++e) f[j * 8 + e] = (float)v[e];
    }

    float m = f[0];
#pragma unroll
    for (int i = 1; i < 16; ++i) m = fmaxf(m, f[i]);
#pragma unroll
    for (int off = 32; off > 0; off >>= 1) m = fmaxf(m, __shfl_xor(m, off));

    __shared__ float redm[4], reds[4];
    const int w = tid >> 6, l = tid & 63;
    if (l == 0) redm[w] = m;
    __syncthreads();
    m = fmaxf(fmaxf(redm[0], redm[1]), fmaxf(redm[2], redm[3]));

    float s = 0.f;
#pragma unroll
    for (int i = 0; i < 16; ++i) { f[i] = __expf(f[i] - m); s += f[i]; }
#pragma unroll
    for (int off = 32; off > 0; off >>= 1) s += __shfl_xor(s, off);
    if (l == 0) reds[w] = s;
    __syncthreads();
    s = (reds[0] + reds[1]) + (reds[2] + reds[3]);
    const float inv = 1.0f / s;

    ushort* prow = (ushort*)Sbase + (size_t)row * SEQ;
#pragma unroll
    for (int j = 0; j < 2; ++j) {
        s16x8 o;
#pragma unroll
        for (int e = 0; e < 8; ++e) o[e] = (short)f2bf(f[j * 8 + e] * inv);
        *(s16x8*)(prow + (size_t)(tid + j * 256) * 8) = o;
    }
}

// ---------------------------------------------------------------------------
extern "C" void kernel_launch(void* const* d_in, const int* in_sizes, int n_in,
                              void* d_out, int out_size, void* d_ws, size_t ws_size,
                              hipStream_t stream)
{
    const float* x  = (const float*)d_in[0];
    const float* wq = (const float*)d_in[1];
    const float* bq = (const float*)d_in[2];
    const float* wk = (const float*)d_in[3];
    const float* bk = (const float*)d_in[4];
    const float* wv = (const float*)d_in[5];
    const float* bv = (const float*)d_in[6];

    char* ws = (char*)d_ws;
    const size_t MB = 1024 * 1024;
    // layout (56 MB total):
    //  [0,8)    Qb   bf16 [4096][1024]   (pre-scaled by 1/sqrt(D))
    //  [8,16)   Kb   bf16 [4096][1024]
    //  [16,24)  Vt   bf16 [1024][4096]   (V transposed, computed directly)
    //  [24,56)  S    fp16 [4096][4096] -> P bf16 in-place (same stride)
    //  [24,32)  xb   bf16 (dead before S written)
    //  [32,38)  wqb/wkb/wvb bf16 (dead before S written)
    ushort* Qb  = (ushort*)(ws);
    ushort* Kb  = (ushort*)(ws + 8 * MB);
    ushort* Vt  = (ushort*)(ws + 16 * MB);
    void*   Sm  = (void*)(ws + 24 * MB);
    ushort* P   = (ushort*)(ws + 24 * MB);
    ushort* xb  = (ushort*)(ws + 24 * MB);
    ushort* wqb = (ushort*)(ws + 32 * MB);
    ushort* wkb = (ushort*)(ws + 34 * MB);
    ushort* wvb = (ushort*)(ws + 36 * MB);

    // ---- converts ----
    cvt_bf16<<<dim3((SEQ * DM / 4 + 255) / 256), dim3(256), 0, stream>>>(x, xb, SEQ * DM / 4);
    cvt_bf16<<<dim3((DM * DM / 4 + 255) / 256), dim3(256), 0, stream>>>(wq, wqb, DM * DM / 4);
    cvt_bf16<<<dim3((DM * DM / 4 + 255) / 256), dim3(256), 0, stream>>>(wk, wkb, DM * DM / 4);
    cvt_bf16<<<dim3((DM * DM / 4 + 255) / 256), dim3(256), 0, stream>>>(wv, wvb, DM * DM / 4);

    const dim3 blk(256);
    // ---- QKV ----
    // Q = (x @ wq^T + bq) * (1/32), bf16 [4096][1024]
    gemm_bt<1, 1><<<dim3(DM / 128, SEQ / 128), blk, 0, stream>>>(
        xb, DM, wqb, DM, bq, Qb, DM, DM, 0.03125f);
    // K = x @ wk^T + bk
    gemm_bt<1, 1><<<dim3(DM / 128, SEQ / 128), blk, 0, stream>>>(
        xb, DM, wkb, DM, bk, Kb, DM, DM, 1.0f);
    // Vt = wv @ x^T + bv[row]  -> V^T [1024][4096]
    gemm_bt<2, 1><<<dim3(SEQ / 128, DM / 128), blk, 0, stream>>>(
        wvb, DM, xb, DM, bv, Vt, SEQ, DM, 1.0f);

    // ---- scores: S = Qs @ K^T, fp16 [4096][4096] ----
    gemm_bt<0, 2><<<dim3(SEQ / 128, SEQ / 128), blk, 0, stream>>>(
        Qb, DM, Kb, DM, nullptr, Sm, SEQ, DM, 1.0f);

    // ---- softmax rows (in-place S fp16 -> P bf16) ----
    softmax_rows<<<dim3(SEQ), blk, 0, stream>>>(Sm);

    // ---- out = P @ Vt^T -> fp32 d_out ----
    gemm_bt<0, 0><<<dim3(DM / 128, SEQ / 128), blk, 0, stream>>>(
        P, SEQ, Vt, SEQ, nullptr, d_out, DM, SEQ, 1.0f);
}

// Round 6
// 237.115 us; speedup vs baseline: 1.0713x; 1.0713x over previous
//
#include <hip/hip_runtime.h>
#include <hip/hip_bf16.h>
#include <stdint.h>

#define SEQ 4096
#define DM  1024

typedef __attribute__((ext_vector_type(8))) short  s16x8;
typedef __attribute__((ext_vector_type(8))) _Float16 h16x8;
typedef __attribute__((ext_vector_type(4))) float  f32x4;

__device__ __forceinline__ ushort f2bf(float f) {
    union { float f; uint32_t u; } x; x.f = f;
    uint32_t r = x.u + 0x7fffu + ((x.u >> 16) & 1u);
    return (ushort)(r >> 16);
}

__device__ __forceinline__ void gload16(const void* g, void* l) {
    __builtin_amdgcn_global_load_lds(
        (const __attribute__((address_space(1))) void*)g,
        (__attribute__((address_space(3))) void*)l,
        16, 0, 0);
}

// ---------------------------------------------------------------------------
// fp32 -> bf16 convert (vectorized float4 -> 4x bf16)
// ---------------------------------------------------------------------------
__global__ __launch_bounds__(256) void cvt_bf16(const float* __restrict__ in,
                                                ushort* __restrict__ out, int n4) {
    int i = blockIdx.x * blockDim.x + threadIdx.x;
    if (i < n4) {
        float4 v = ((const float4*)in)[i];
        ushort4 o;
        o.x = f2bf(v.x); o.y = f2bf(v.y); o.z = f2bf(v.z); o.w = f2bf(v.w);
        ((ushort4*)out)[i] = o;
    }
}

// ---------------------------------------------------------------------------
// GEMM: C[M,N] = A[M,K] * B[N,K]^T (both row-major, leading dim = K stride).
// 128x128 tile, BK=32, 4 waves (each 64x64 = 4x4 frags of 16x16x32 bf16 MFMA).
// 2-phase double-buffered pipeline: STAGE(t+1) issued before compute(t), one
// barrier per K-step (T3-minimum recipe). XCD-aware bijective block swizzle.
// BIAS_MODE: 0 none, 1 bias[col], 2 bias[row].  OUT_MODE: 0 f32, 1 bf16, 2 f16
// ---------------------------------------------------------------------------
template<int BIAS_MODE, int OUT_MODE>
__global__ __launch_bounds__(256)
void gemm_bt(const ushort* __restrict__ A, int lda,
             const ushort* __restrict__ B, int ldb,
             const float* __restrict__ bias,
             void* __restrict__ Cout, int ldc,
             int K, float scale, int nbx)
{
    constexpr int BK  = 32;
    constexpr int BUF = 128 * BK;                 // elements per buffer
    __shared__ alignas(16) ushort lsA[2 * BUF];
    __shared__ alignas(16) ushort lsB[2 * BUF];

    // XCD-aware bijective swizzle (grid sizes here are all %8 == 0)
    const int nwg = gridDim.x;
    const int wg  = blockIdx.x;
    const int logical = (wg & 7) * (nwg >> 3) + (wg >> 3);
    const int bx = logical % nbx;
    const int by = logical / nbx;

    const int tid = threadIdx.x;
    const int w   = tid >> 6;
    const int l   = tid & 63;
    const int m0  = by * 128;
    const int n0  = bx * 128;
    const int wm  = (w >> 1) * 64;   // wave row offset in tile
    const int wn  = (w & 1) * 64;    // wave col offset in tile

    // staging: each wave stages 16 rows per chunk, 2 chunks per matrix
    const int sr = l >> 2;           // row within 16-row chunk
    const int sc = (l & 3) * 8;      // col (elements)

    const ushort* gA0 = A + (size_t)(m0 + w * 16 + sr) * lda + sc;
    const ushort* gA1 = gA0 + (size_t)64 * lda;
    const ushort* gB0 = B + (size_t)(n0 + w * 16 + sr) * ldb + sc;
    const ushort* gB1 = gB0 + (size_t)64 * ldb;
    ushort* lA0 = &lsA[(w * 16) * BK];
    ushort* lA1 = &lsA[(64 + w * 16) * BK];
    ushort* lB0 = &lsB[(w * 16) * BK];
    ushort* lB1 = &lsB[(64 + w * 16) * BK];

    const int lr = l & 15;           // fragment row/col within 16
    const int kh = (l >> 4) * 8;     // fragment k offset

    f32x4 acc[4][4] = {};

    const int nt = K / BK;

    // prologue: stage tile 0 into buffer 0
    gload16(gA0, lA0);
    gload16(gA1, lA1);
    gload16(gB0, lB0);
    gload16(gB1, lB1);
    __syncthreads();                  // drains vmcnt+lgkmcnt

    int cur = 0;
    for (int t = 0; t < nt - 1; ++t) {
        // ---- prefetch tile t+1 into the other buffer (overlaps compute) ----
        const int k = (t + 1) * BK;
        const int po = (cur ^ 1) * BUF;
        gload16(gA0 + k, lA0 + po);
        gload16(gA1 + k, lA1 + po);
        gload16(gB0 + k, lB0 + po);
        gload16(gB1 + k, lB1 + po);

        // ---- compute tile t from buf[cur] ----
        const int co = cur * BUF;
        s16x8 af[4], bfr[4];
#pragma unroll
        for (int i = 0; i < 4; ++i)
            af[i] = *(const s16x8*)&lsA[co + (wm + i * 16 + lr) * BK + kh];
#pragma unroll
        for (int j = 0; j < 4; ++j)
            bfr[j] = *(const s16x8*)&lsB[co + (wn + j * 16 + lr) * BK + kh];
#pragma unroll
        for (int i = 0; i < 4; ++i)
#pragma unroll
            for (int j = 0; j < 4; ++j)
                acc[i][j] = __builtin_amdgcn_mfma_f32_16x16x32_bf16(af[i], bfr[j], acc[i][j], 0, 0, 0);

        __syncthreads();              // drains prefetch vmcnt; buf ready
        cur ^= 1;
    }

    // ---- last tile (no prefetch) ----
    {
        const int co = cur * BUF;
        s16x8 af[4], bfr[4];
#pragma unroll
        for (int i = 0; i < 4; ++i)
            af[i] = *(const s16x8*)&lsA[co + (wm + i * 16 + lr) * BK + kh];
#pragma unroll
        for (int j = 0; j < 4; ++j)
            bfr[j] = *(const s16x8*)&lsB[co + (wn + j * 16 + lr) * BK + kh];
#pragma unroll
        for (int i = 0; i < 4; ++i)
#pragma unroll
            for (int j = 0; j < 4; ++j)
                acc[i][j] = __builtin_amdgcn_mfma_f32_16x16x32_bf16(af[i], bfr[j], acc[i][j], 0, 0, 0);
    }

    // epilogue: C/D layout col = lane&15, row = (lane>>4)*4 + r  (m91-verified)
    const int r0 = m0 + wm + ((l >> 4) << 2);
    const int c0 = n0 + wn + lr;
#pragma unroll
    for (int i = 0; i < 4; ++i) {
#pragma unroll
        for (int j = 0; j < 4; ++j) {
#pragma unroll
            for (int r = 0; r < 4; ++r) {
                const int row = r0 + i * 16 + r;
                const int col = c0 + j * 16;
                float v = acc[i][j][r];
                if (BIAS_MODE == 1) v += bias[col];
                if (BIAS_MODE == 2) v += bias[row];
                v *= scale;
                if (OUT_MODE == 0)      ((float*)Cout)[(size_t)row * ldc + col] = v;
                else if (OUT_MODE == 1) ((ushort*)Cout)[(size_t)row * ldc + col] = f2bf(v);
                else                    ((_Float16*)Cout)[(size_t)row * ldc + col] = (_Float16)v;
            }
        }
    }
}

// ---------------------------------------------------------------------------
// Row softmax: S (fp16, [4096][4096]) -> P (bf16) written IN-PLACE (each
// thread rewrites exactly the 16B chunks it read). fp32 math throughout.
// ---------------------------------------------------------------------------
__global__ __launch_bounds__(256) void softmax_rows(void* __restrict__ Sbase) {
    const int row = blockIdx.x;
    const int tid = threadIdx.x;
    const _Float16* srow = (const _Float16*)Sbase + (size_t)row * SEQ;

    float f[16];
#pragma unroll
    for (int j = 0; j < 2; ++j) {
        h16x8 v = *(const h16x8*)(srow + (size_t)(tid + j * 256) * 8);
#pragma unroll
        for (int e = 0; e < 8; ++e) f[j * 8 + e] = (float)v[e];
    }

    float m = f[0];
#pragma unroll
    for (int i = 1; i < 16; ++i) m = fmaxf(m, f[i]);
#pragma unroll
    for (int off = 32; off > 0; off >>= 1) m = fmaxf(m, __shfl_xor(m, off));

    __shared__ float redm[4], reds[4];
    const int w = tid >> 6, l = tid & 63;
    if (l == 0) redm[w] = m;
    __syncthreads();
    m = fmaxf(fmaxf(redm[0], redm[1]), fmaxf(redm[2], redm[3]));

    float s = 0.f;
#pragma unroll
    for (int i = 0; i < 16; ++i) { f[i] = __expf(f[i] - m); s += f[i]; }
#pragma unroll
    for (int off = 32; off > 0; off >>= 1) s += __shfl_xor(s, off);
    if (l == 0) reds[w] = s;
    __syncthreads();
    s = (reds[0] + reds[1]) + (reds[2] + reds[3]);
    const float inv = 1.0f / s;

    ushort* prow = (ushort*)Sbase + (size_t)row * SEQ;
#pragma unroll
    for (int j = 0; j < 2; ++j) {
        s16x8 o;
#pragma unroll
        for (int e = 0; e < 8; ++e) o[e] = (short)f2bf(f[j * 8 + e] * inv);
        *(s16x8*)(prow + (size_t)(tid + j * 256) * 8) = o;
    }
}

// ---------------------------------------------------------------------------
extern "C" void kernel_launch(void* const* d_in, const int* in_sizes, int n_in,
                              void* d_out, int out_size, void* d_ws, size_t ws_size,
                              hipStream_t stream)
{
    const float* x  = (const float*)d_in[0];
    const float* wq = (const float*)d_in[1];
    const float* bq = (const float*)d_in[2];
    const float* wk = (const float*)d_in[3];
    const float* bk = (const float*)d_in[4];
    const float* wv = (const float*)d_in[5];
    const float* bv = (const float*)d_in[6];

    char* ws = (char*)d_ws;
    const size_t MB = 1024 * 1024;
    // layout (56 MB total):
    //  [0,8)    Qb   bf16 [4096][1024]   (pre-scaled by 1/sqrt(D))
    //  [8,16)   Kb   bf16 [4096][1024]
    //  [16,24)  Vt   bf16 [1024][4096]   (V transposed, computed directly)
    //  [24,56)  S    fp16 [4096][4096] -> P bf16 in-place (same stride)
    //  [24,32)  xb   bf16 (dead before S written)
    //  [32,38)  wqb/wkb/wvb bf16 (dead before S written)
    ushort* Qb  = (ushort*)(ws);
    ushort* Kb  = (ushort*)(ws + 8 * MB);
    ushort* Vt  = (ushort*)(ws + 16 * MB);
    void*   Sm  = (void*)(ws + 24 * MB);
    ushort* P   = (ushort*)(ws + 24 * MB);
    ushort* xb  = (ushort*)(ws + 24 * MB);
    ushort* wqb = (ushort*)(ws + 32 * MB);
    ushort* wkb = (ushort*)(ws + 34 * MB);
    ushort* wvb = (ushort*)(ws + 36 * MB);

    // ---- converts ----
    cvt_bf16<<<dim3((SEQ * DM / 4 + 255) / 256), dim3(256), 0, stream>>>(x, xb, SEQ * DM / 4);
    cvt_bf16<<<dim3((DM * DM / 4 + 255) / 256), dim3(256), 0, stream>>>(wq, wqb, DM * DM / 4);
    cvt_bf16<<<dim3((DM * DM / 4 + 255) / 256), dim3(256), 0, stream>>>(wk, wkb, DM * DM / 4);
    cvt_bf16<<<dim3((DM * DM / 4 + 255) / 256), dim3(256), 0, stream>>>(wv, wvb, DM * DM / 4);

    const dim3 blk(256);
    // ---- QKV ----  (1D grids, swizzled internally; all grids %8==0)
    // Q = (x @ wq^T + bq) * (1/32), bf16 [4096][1024]
    gemm_bt<1, 1><<<dim3((DM / 128) * (SEQ / 128)), blk, 0, stream>>>(
        xb, DM, wqb, DM, bq, Qb, DM, DM, 0.03125f, DM / 128);
    // K = x @ wk^T + bk
    gemm_bt<1, 1><<<dim3((DM / 128) * (SEQ / 128)), blk, 0, stream>>>(
        xb, DM, wkb, DM, bk, Kb, DM, DM, 1.0f, DM / 128);
    // Vt = wv @ x^T + bv[row]  -> V^T [1024][4096]
    gemm_bt<2, 1><<<dim3((SEQ / 128) * (DM / 128)), blk, 0, stream>>>(
        wvb, DM, xb, DM, bv, Vt, SEQ, DM, 1.0f, SEQ / 128);

    // ---- scores: S = Qs @ K^T, fp16 [4096][4096] ----
    gemm_bt<0, 2><<<dim3((SEQ / 128) * (SEQ / 128)), blk, 0, stream>>>(
        Qb, DM, Kb, DM, nullptr, Sm, SEQ, DM, 1.0f, SEQ / 128);

    // ---- softmax rows (in-place S fp16 -> P bf16) ----
    softmax_rows<<<dim3(SEQ), blk, 0, stream>>>(Sm);

    // ---- out = P @ Vt^T -> fp32 d_out ----
    gemm_bt<0, 0><<<dim3((DM / 128) * (SEQ / 128)), blk, 0, stream>>>(
        P, SEQ, Vt, SEQ, nullptr, d_out, DM, SEQ, 1.0f, DM / 128);
}

// Round 7
// 161.608 us; speedup vs baseline: 1.5718x; 1.4672x over previous
//
#include <hip/hip_runtime.h>
#include <hip/hip_bf16.h>
#include <stdint.h>

#define SEQ 4096
#define DM  1024

typedef __attribute__((ext_vector_type(8))) short  s16x8;
typedef __attribute__((ext_vector_type(8))) _Float16 h16x8;
typedef __attribute__((ext_vector_type(4))) float  f32x4;

__device__ __forceinline__ ushort f2bf(float f) {
    union { float f; uint32_t u; } x; x.f = f;
    uint32_t r = x.u + 0x7fffu + ((x.u >> 16) & 1u);
    return (ushort)(r >> 16);
}

__device__ __forceinline__ void gload16(const void* g, void* l) {
    __builtin_amdgcn_global_load_lds(
        (const __attribute__((address_space(1))) void*)g,
        (__attribute__((address_space(3))) void*)l,
        16, 0, 0);
}

// ---------------------------------------------------------------------------
__global__ __launch_bounds__(256) void cvt_bf16(const float* __restrict__ in,
                                                ushort* __restrict__ out, int n4) {
    int i = blockIdx.x * blockDim.x + threadIdx.x;
    if (i < n4) {
        float4 v = ((const float4*)in)[i];
        ushort4 o;
        o.x = f2bf(v.x); o.y = f2bf(v.y); o.z = f2bf(v.z); o.w = f2bf(v.w);
        ((ushort4*)out)[i] = o;
    }
}

// ===========================================================================
// 256x256 8-phase GEMM for scores: S[4096][4096](f16) = Q[4096][1024] * K^T.
// K=1024, BK=64, 8 waves (2Mx4N), LDS 128KB (2 dbuf x 4 x 16KB K-half regions
// [256 rows][32 cols] with st_16x32 XOR swizzle). Counted vmcnt(4) at phases
// 4/8 only; stage half p+6 at phase p (write target provably dead >=1 phase).
// ===========================================================================
__global__ __launch_bounds__(512, 1)
void gemm256_score(const ushort* __restrict__ Q, const ushort* __restrict__ Km,
                   _Float16* __restrict__ S)
{
    constexpr int NT = DM / 64;         // 16 K-tiles
    constexpr int TOTAL_H = NT * 4;     // 64 halves
    __shared__ ushort lds_u[65536];     // 128 KB
    char* lb = (char*)lds_u;

    // XCD-aware swizzle, grid = 256
    const int wg = blockIdx.x;
    const int logical = (wg & 7) * 32 + (wg >> 3);
    const int bx = logical & 15;
    const int by = logical >> 4;
    const int m0 = by * 256, n0 = bx * 256;

    const int tid = threadIdx.x;
    const int w = tid >> 6, l = tid & 63;
    const int wr = w >> 2, wc = w & 3;          // wave -> 128x64 output
    const int lm = l & 15;
    const int khb = (l >> 4) * 16;              // k byte offset within half

    const ushort* Ab = Q  + (size_t)m0 * DM;
    const ushort* Bb = Km + (size_t)n0 * DM;

    // staging decode: LDS[linear o] <- global(rc(swz(o))) ; swz = xor bit5 by bit9
    const int in0 = tid * 16, in1 = 8192 + tid * 16;
    const int b0 = in0 ^ (((in0 >> 9) & 1) << 5);
    const int b1 = in1 ^ (((in1 >> 9) & 1) << 5);
    const int r0_ = b0 >> 6, c0_ = (b0 & 63) >> 1;
    const int r1_ = b1 >> 6, c1_ = (b1 & 63) >> 1;

    // ds-read bases (thread-constant); swizzle bit depends only on lm bit3
    const int swzb = ((lm >> 3) & 1) << 5;
    const int aoff = (((wr * 128 + lm) * 64 + khb) ^ swzb);
    const int boff = (((wc * 64 + lm) * 64 + khb) ^ swzb);

    f32x4 acc[8][4] = {};
    s16x8 bq[4];

#define RBASE(buf, region) ((buf) * 65536 + (region) * 16384)

#define STAGE_H(g) do { \
    const int hidx_ = (g) - 1; const int tile_ = hidx_ >> 2; const int reg_ = hidx_ & 3; \
    const ushort* mp_ = (reg_ & 1) ? Bb : Ab; \
    const int colb_ = tile_ * 64 + (reg_ >> 1) * 32; \
    char* dst_ = lb + RBASE(tile_ & 1, reg_); \
    gload16(mp_ + (size_t)r0_ * DM + colb_ + c0_, dst_ + in0); \
    gload16(mp_ + (size_t)r1_ * DM + colb_ + c1_, dst_ + in1); \
} while (0)

#define PHASE(ph, kt2) do { \
    constexpr int kk_   = (((ph) - 1) >> 1) & 1; \
    constexpr int mh_   = ((ph) - 1) & 1; \
    constexpr int rbuf_ = ((ph) <= 4) ? 0 : 1; \
    constexpr int areg_ = kk_ * 2; \
    constexpr int breg_ = kk_ * 2 + 1; \
    s16x8 aq[4]; \
    if (mh_ == 0) { \
        _Pragma("unroll") \
        for (int nj = 0; nj < 4; ++nj) \
            bq[nj] = *(const s16x8*)(lb + RBASE(rbuf_, breg_) + boff + nj * 1024); \
    } \
    _Pragma("unroll") \
    for (int i = 0; i < 4; ++i) \
        aq[i] = *(const s16x8*)(lb + RBASE(rbuf_, areg_) + aoff + (mh_ * 4 + i) * 1024); \
    { const int g_ = (kt2) * 8 + (ph) + 6; if (g_ <= TOTAL_H) STAGE_H(g_); } \
    __builtin_amdgcn_s_barrier(); \
    asm volatile("s_waitcnt lgkmcnt(0)" ::: "memory"); \
    __builtin_amdgcn_sched_barrier(0); \
    __builtin_amdgcn_s_setprio(1); \
    _Pragma("unroll") \
    for (int i = 0; i < 4; ++i) { \
        _Pragma("unroll") \
        for (int nj = 0; nj < 4; ++nj) \
            acc[mh_ * 4 + i][nj] = __builtin_amdgcn_mfma_f32_16x16x32_bf16( \
                aq[i], bq[nj], acc[mh_ * 4 + i][nj], 0, 0, 0); \
    } \
    __builtin_amdgcn_s_setprio(0); \
    if ((ph) == 4 || (ph) == 8) asm volatile("s_waitcnt vmcnt(4)" ::: "memory"); \
    __builtin_amdgcn_s_barrier(); \
} while (0)

    // prologue: stage halves 1..6, ensure tile0 (halves 1-4) complete
    STAGE_H(1); STAGE_H(2); STAGE_H(3); STAGE_H(4); STAGE_H(5); STAGE_H(6);
    asm volatile("s_waitcnt vmcnt(4)" ::: "memory");
    __builtin_amdgcn_s_barrier();

    for (int kt2 = 0; kt2 < NT / 2; ++kt2) {
        PHASE(1, kt2); PHASE(2, kt2); PHASE(3, kt2); PHASE(4, kt2);
        PHASE(5, kt2); PHASE(6, kt2); PHASE(7, kt2); PHASE(8, kt2);
    }

    // epilogue: C/D layout col = lane&15, row = (lane>>4)*4 + r
    const int er0 = m0 + wr * 128 + (l >> 4) * 4;
    const int ec0 = n0 + wc * 64 + lm;
#pragma unroll
    for (int mi = 0; mi < 8; ++mi)
#pragma unroll
        for (int nj = 0; nj < 4; ++nj)
#pragma unroll
            for (int r = 0; r < 4; ++r)
                S[(size_t)(er0 + mi * 16 + r) * SEQ + ec0 + nj * 16] =
                    (_Float16)acc[mi][nj][r];
#undef PHASE
#undef STAGE_H
#undef RBASE
}

// ===========================================================================
// 128x128 GEMM, BK=64, static two-buffer 2-phase, swizzled LDS (4-way max).
// C = A[M,K] * B[N,K]^T. BIAS_MODE: 0 none, 1 bias[col], 2 bias[row].
// OUT_MODE: 0 f32, 1 bf16.
// ===========================================================================
template<int BIAS_MODE, int OUT_MODE>
__global__ __launch_bounds__(256)
void gemm128(const ushort* __restrict__ A, int lda,
             const ushort* __restrict__ B, int ldb,
             const float* __restrict__ bias,
             void* __restrict__ Cout, int ldc,
             int K, float scale, int nbx)
{
    __shared__ ushort lds_u[32768];     // 64 KB: 2 buf x (A 16K + B 16K)
    char* lb = (char*)lds_u;

    const int nwg = gridDim.x;
    const int wg  = blockIdx.x;
    const int logical = (wg & 7) * (nwg >> 3) + (wg >> 3);
    const int bx = logical % nbx, by = logical / nbx;
    const int m0 = by * 128, n0 = bx * 128;

    const int tid = threadIdx.x;
    const int w = tid >> 6, l = tid & 63;
    const int wm = (w >> 1) * 64, wn = (w & 1) * 64;
    const int lm = l & 15;
    const int khb = (l >> 4) * 16;
    const int swzb = ((lm >> 3) & 1) << 5;
    const int aoff = ((wm + lm) * 64 + khb) ^ swzb;
    const int boff = ((wn + lm) * 64 + khb) ^ swzb;

    // staging decode: 4 slots/matrix; inner = i*4096 + tid*16 within [2][128][32]
    int rr[4], cc[4];
#pragma unroll
    for (int i = 0; i < 4; ++i) {
        const int rest = (i & 1) * 4096 + tid * 16;       // within 8KB k-half
        const int b = rest ^ (((rest >> 9) & 1) << 5);
        rr[i] = b >> 6; cc[i] = (b & 63) >> 1;
    }

#define STAGE128(t_, buf_) do { \
    const int colt_ = (t_) * 64; \
    _Pragma("unroll") \
    for (int i = 0; i < 4; ++i) { \
        const int ldso_ = (i >> 1) * 8192 + (i & 1) * 4096 + tid * 16; \
        gload16(A + (size_t)(m0 + rr[i]) * lda + colt_ + (i >> 1) * 32 + cc[i], \
                lb + (buf_) * 32768 + ldso_); \
        gload16(B + (size_t)(n0 + rr[i]) * ldb + colt_ + (i >> 1) * 32 + cc[i], \
                lb + (buf_) * 32768 + 16384 + ldso_); \
    } \
} while (0)

    f32x4 acc[4][4] = {};

#define COMPUTE128(buf_) do { \
    _Pragma("unroll") \
    for (int kk = 0; kk < 2; ++kk) { \
        s16x8 a_[4], b_[4]; \
        _Pragma("unroll") \
        for (int i = 0; i < 4; ++i) \
            a_[i] = *(const s16x8*)(lb + (buf_) * 32768 + kk * 8192 + aoff + i * 1024); \
        _Pragma("unroll") \
        for (int j = 0; j < 4; ++j) \
            b_[j] = *(const s16x8*)(lb + (buf_) * 32768 + 16384 + kk * 8192 + boff + j * 1024); \
        _Pragma("unroll") \
        for (int i = 0; i < 4; ++i) { \
            _Pragma("unroll") \
            for (int j = 0; j < 4; ++j) \
                acc[i][j] = __builtin_amdgcn_mfma_f32_16x16x32_bf16(a_[i], b_[j], acc[i][j], 0, 0, 0); \
        } \
    } \
} while (0)

    const int NT = K / 64;
    STAGE128(0, 0);
    __syncthreads();
    int t = 0;
    for (; t + 2 < NT; t += 2) {
        STAGE128(t + 1, 1); COMPUTE128(0); __syncthreads();
        STAGE128(t + 2, 0); COMPUTE128(1); __syncthreads();
    }
    STAGE128(NT - 1, 1); COMPUTE128(0); __syncthreads();
    COMPUTE128(1);

    const int r0 = m0 + wm + ((l >> 4) << 2);
    const int c0 = n0 + wn + lm;
#pragma unroll
    for (int i = 0; i < 4; ++i) {
#pragma unroll
        for (int j = 0; j < 4; ++j) {
#pragma unroll
            for (int r = 0; r < 4; ++r) {
                const int row = r0 + i * 16 + r;
                const int col = c0 + j * 16;
                float v = acc[i][j][r];
                if (BIAS_MODE == 1) v += bias[col];
                if (BIAS_MODE == 2) v += bias[row];
                v *= scale;
                if (OUT_MODE == 0) ((float*)Cout)[(size_t)row * ldc + col] = v;
                else               ((ushort*)Cout)[(size_t)row * ldc + col] = f2bf(v);
            }
        }
    }
#undef STAGE128
#undef COMPUTE128
}

// ---------------------------------------------------------------------------
// Row softmax: S (fp16) -> P (bf16) in-place, fp32 math.
// ---------------------------------------------------------------------------
__global__ __launch_bounds__(256) void softmax_rows(void* __restrict__ Sbase) {
    const int row = blockIdx.x;
    const int tid = threadIdx.x;
    const _Float16* srow = (const _Float16*)Sbase + (size_t)row * SEQ;

    float f[16];
#pragma unroll
    for (int j = 0; j < 2; ++j) {
        h16x8 v = *(const h16x8*)(srow + (size_t)(tid + j * 256) * 8);
#pragma unroll
        for (int e = 0; e < 8; ++e) f[j * 8 + e] = (float)v[e];
    }

    float m = f[0];
#pragma unroll
    for (int i = 1; i < 16; ++i) m = fmaxf(m, f[i]);
#pragma unroll
    for (int off = 32; off > 0; off >>= 1) m = fmaxf(m, __shfl_xor(m, off));

    __shared__ float redm[4], reds[4];
    const int w = tid >> 6, l = tid & 63;
    if (l == 0) redm[w] = m;
    __syncthreads();
    m = fmaxf(fmaxf(redm[0], redm[1]), fmaxf(redm[2], redm[3]));

    float s = 0.f;
#pragma unroll
    for (int i = 0; i < 16; ++i) { f[i] = __expf(f[i] - m); s += f[i]; }
#pragma unroll
    for (int off = 32; off > 0; off >>= 1) s += __shfl_xor(s, off);
    if (l == 0) reds[w] = s;
    __syncthreads();
    s = (reds[0] + reds[1]) + (reds[2] + reds[3]);
    const float inv = 1.0f / s;

    ushort* prow = (ushort*)Sbase + (size_t)row * SEQ;
#pragma unroll
    for (int j = 0; j < 2; ++j) {
        s16x8 o;
#pragma unroll
        for (int e = 0; e < 8; ++e) o[e] = (short)f2bf(f[j * 8 + e] * inv);
        *(s16x8*)(prow + (size_t)(tid + j * 256) * 8) = o;
    }
}

// ---------------------------------------------------------------------------
extern "C" void kernel_launch(void* const* d_in, const int* in_sizes, int n_in,
                              void* d_out, int out_size, void* d_ws, size_t ws_size,
                              hipStream_t stream)
{
    const float* x  = (const float*)d_in[0];
    const float* wq = (const float*)d_in[1];
    const float* bq = (const float*)d_in[2];
    const float* wk = (const float*)d_in[3];
    const float* bk = (const float*)d_in[4];
    const float* wv = (const float*)d_in[5];
    const float* bv = (const float*)d_in[6];

    char* ws = (char*)d_ws;
    const size_t MB = 1024 * 1024;
    ushort* Qb  = (ushort*)(ws);
    ushort* Kb  = (ushort*)(ws + 8 * MB);
    ushort* Vt  = (ushort*)(ws + 16 * MB);
    void*   Sm  = (void*)(ws + 24 * MB);
    ushort* P   = (ushort*)(ws + 24 * MB);
    ushort* xb  = (ushort*)(ws + 24 * MB);
    ushort* wqb = (ushort*)(ws + 32 * MB);
    ushort* wkb = (ushort*)(ws + 34 * MB);
    ushort* wvb = (ushort*)(ws + 36 * MB);

    cvt_bf16<<<dim3((SEQ * DM / 4 + 255) / 256), dim3(256), 0, stream>>>(x, xb, SEQ * DM / 4);
    cvt_bf16<<<dim3((DM * DM / 4 + 255) / 256), dim3(256), 0, stream>>>(wq, wqb, DM * DM / 4);
    cvt_bf16<<<dim3((DM * DM / 4 + 255) / 256), dim3(256), 0, stream>>>(wk, wkb, DM * DM / 4);
    cvt_bf16<<<dim3((DM * DM / 4 + 255) / 256), dim3(256), 0, stream>>>(wv, wvb, DM * DM / 4);

    const dim3 blk(256);
    // Q = (x @ wq^T + bq) * (1/32)  [4096][1024] bf16
    gemm128<1, 1><<<dim3(256), blk, 0, stream>>>(xb, DM, wqb, DM, bq, Qb, DM, DM, 0.03125f, 8);
    // K = x @ wk^T + bk
    gemm128<1, 1><<<dim3(256), blk, 0, stream>>>(xb, DM, wkb, DM, bk, Kb, DM, DM, 1.0f, 8);
    // Vt = wv @ x^T + bv[row]  -> V^T [1024][4096]
    gemm128<2, 1><<<dim3(256), blk, 0, stream>>>(wvb, DM, xb, DM, bv, Vt, SEQ, DM, 1.0f, 32);

    // scores: S = Qs @ K^T, fp16 [4096][4096] (8-phase 256^2)
    gemm256_score<<<dim3(256), dim3(512), 0, stream>>>(Qb, Kb, (_Float16*)Sm);

    // softmax rows (in-place fp16 -> bf16)
    softmax_rows<<<dim3(SEQ), blk, 0, stream>>>(Sm);

    // out = P @ Vt^T -> fp32 d_out
    gemm128<0, 0><<<dim3(256), blk, 0, stream>>>(P, SEQ, Vt, SEQ, nullptr, d_out, DM, SEQ, 1.0f, 8);
}

// Round 8
// 141.978 us; speedup vs baseline: 1.7891x; 1.1383x over previous
//
#include <hip/hip_runtime.h>
#include <hip/hip_bf16.h>
#include <stdint.h>

#define SEQ 4096
#define DM  1024

typedef __attribute__((ext_vector_type(8))) short  s16x8;
typedef __attribute__((ext_vector_type(8))) _Float16 h16x8;
typedef __attribute__((ext_vector_type(4))) float  f32x4;

__device__ __forceinline__ ushort f2bf(float f) {
    union { float f; uint32_t u; } x; x.f = f;
    uint32_t r = x.u + 0x7fffu + ((x.u >> 16) & 1u);
    return (ushort)(r >> 16);
}

__device__ __forceinline__ void gload16(const void* g, void* l) {
    __builtin_amdgcn_global_load_lds(
        (const __attribute__((address_space(1))) void*)g,
        (__attribute__((address_space(3))) void*)l,
        16, 0, 0);
}

// ---------------------------------------------------------------------------
// fused fp32->bf16 convert of x + wq + wk + wv (one launch)
// i in [0, 1048576) -> x float4s; then 3 x 262144 float4s for the weights.
// ---------------------------------------------------------------------------
__global__ __launch_bounds__(256)
void cvt_all(const float* __restrict__ x,  const float* __restrict__ wq,
             const float* __restrict__ wk, const float* __restrict__ wv,
             ushort* __restrict__ xb,  ushort* __restrict__ wqb,
             ushort* __restrict__ wkb, ushort* __restrict__ wvb)
{
    int i = blockIdx.x * 256 + threadIdx.x;      // grid sized exactly
    const float* src; ushort* dst; int k;
    if (i < 1048576) { src = x; dst = xb; k = i; }
    else {
        int j = i - 1048576; int w = j >> 18; k = j & 262143;
        src = (w == 0) ? wq : (w == 1) ? wk : wv;
        dst = (w == 0) ? wqb : (w == 1) ? wkb : wvb;
    }
    float4 v = ((const float4*)src)[k];
    ushort4 o;
    o.x = f2bf(v.x); o.y = f2bf(v.y); o.z = f2bf(v.z); o.w = f2bf(v.w);
    ((ushort4*)dst)[k] = o;
}

// ===========================================================================
// 8-phase 256-row GEMM template (C = A[M,K] * B[N,K]^T, bf16 in, f16 out).
// MODE 0: scores  — BN=256, lda=1024, 16 K-tiles, grid 256 (16x16 tiles).
// MODE 1: PV split-K=2 — BN=128, lda=4096, 32 K-tiles (K-slice 2048),
//         grid 256 (16x8 tiles x 2 splits), C = Cbase + ks*4M elems.
// Schedule (verified round 7 as MODE 0): stage half p+6 at phase p, counted
// vmcnt at phases 4/8 only, st_16x32 XOR swizzle, setprio around MFMA.
// ===========================================================================
template<int MODE>
__global__ __launch_bounds__(512, 1)
void gemm256p(const ushort* __restrict__ A, const ushort* __restrict__ B,
              _Float16* __restrict__ Cbase, int lda, int ldc)
{
    constexpr int BN      = MODE ? 128 : 256;
    constexpr int WN      = BN / 4;              // wave col span
    constexpr int NJ      = BN / 64;             // col frags per wave
    constexpr int REG_A   = 16384;               // A half-tile bytes [256][32]
    constexpr int REG_B   = BN * 32 * 2;         // B half-tile bytes [BN][32]
    constexpr int BUFSZ   = 2 * (REG_A + REG_B);
    constexpr int NTILES  = MODE ? 32 : 16;      // K-tiles per block
    constexpr int TOTAL_H = NTILES * 4;

    __shared__ ushort lds_u[BUFSZ];              // 2 buffers total = BUFSZ*2/2
    char* lb = (char*)lds_u;                     // (BUFSZ bytes *2 buffers)

    // XCD-aware bijective swizzle, grid = 256
    const int wg = blockIdx.x;
    const int logical = (wg & 7) * 32 + (wg >> 3);
    int m0, n0;
    const ushort *Ab, *Bb;
    _Float16* C;
    if constexpr (MODE == 0) {
        const int bx = logical & 15, by = logical >> 4;
        m0 = by * 256; n0 = bx * 256;
        Ab = A + (size_t)m0 * lda;
        Bb = B + (size_t)n0 * lda;
        C  = Cbase;
    } else {
        const int t = logical >> 1, ks = logical & 1;
        const int by = t >> 3, bx = t & 7;
        m0 = by * 256; n0 = bx * 128;
        Ab = A + (size_t)m0 * lda + ks * 2048;
        Bb = B + (size_t)n0 * lda + ks * 2048;
        C  = Cbase + (size_t)ks * (4096 * 1024);
    }

    const int tid = threadIdx.x;
    const int w = tid >> 6, l = tid & 63;
    const int wr = w >> 2, wc = w & 3;
    const int lm = l & 15;
    const int khb = (l >> 4) * 16;

    // staging decode: LDS linear dst, pre-swizzled global src (bit5 ^= bit9)
    const int in0 = tid * 16, in1 = 8192 + tid * 16;
    const int b0 = in0 ^ (((in0 >> 9) & 1) << 5);
    const int b1 = in1 ^ (((in1 >> 9) & 1) << 5);
    const int r0_ = b0 >> 6, c0_ = (b0 & 63) >> 1;
    const int r1_ = b1 >> 6, c1_ = (b1 & 63) >> 1;

    // ds-read bases; swizzle bit depends only on lm bit3
    const int swzb = ((lm >> 3) & 1) << 5;
    const int aoff = (((wr * 128 + lm) * 64 + khb) ^ swzb);
    const int boff = (((wc * WN + lm) * 64 + khb) ^ swzb);

    f32x4 acc[8][NJ] = {};
    s16x8 bq[NJ];

    // region byte offsets within a buffer: A0, B0, A1, B1
    constexpr int roff0 = 0, roff1 = REG_A, roff2 = REG_A + REG_B,
                  roff3 = 2 * REG_A + REG_B;

#define ROFF(reg_) ((reg_) == 0 ? roff0 : (reg_) == 1 ? roff1 : (reg_) == 2 ? roff2 : roff3)

#define STAGE_H(g) do { \
    const int hidx_ = (g) - 1; const int tile_ = hidx_ >> 2; const int reg_ = hidx_ & 3; \
    const int colb_ = tile_ * 64 + (reg_ >> 1) * 32; \
    char* dst_ = lb + (tile_ & 1) * BUFSZ + ROFF(reg_); \
    if (reg_ & 1) { /* B half */ \
        gload16(Bb + (size_t)r0_ * lda + colb_ + c0_, dst_ + in0); \
        if constexpr (MODE == 0) gload16(Bb + (size_t)r1_ * lda + colb_ + c1_, dst_ + in1); \
    } else {        /* A half */ \
        gload16(Ab + (size_t)r0_ * lda + colb_ + c0_, dst_ + in0); \
        gload16(Ab + (size_t)r1_ * lda + colb_ + c1_, dst_ + in1); \
    } \
} while (0)

#define WAITVMC() do { \
    if constexpr (MODE == 0) asm volatile("s_waitcnt vmcnt(4)" ::: "memory"); \
    else                     asm volatile("s_waitcnt vmcnt(3)" ::: "memory"); \
} while (0)

#define PHASE(ph, kt2) do { \
    constexpr int kk_   = (((ph) - 1) >> 1) & 1; \
    constexpr int mh_   = ((ph) - 1) & 1; \
    constexpr int rbuf_ = ((ph) <= 4) ? 0 : 1; \
    constexpr int aro_  = (kk_ == 0) ? roff0 : roff2; \
    constexpr int bro_  = (kk_ == 0) ? roff1 : roff3; \
    s16x8 aq[4]; \
    if (mh_ == 0) { \
        _Pragma("unroll") \
        for (int nj = 0; nj < NJ; ++nj) \
            bq[nj] = *(const s16x8*)(lb + rbuf_ * BUFSZ + bro_ + boff + nj * 1024); \
    } \
    _Pragma("unroll") \
    for (int i = 0; i < 4; ++i) \
        aq[i] = *(const s16x8*)(lb + rbuf_ * BUFSZ + aro_ + aoff + (mh_ * 4 + i) * 1024); \
    { const int g_ = (kt2) * 8 + (ph) + 6; if (g_ <= TOTAL_H) STAGE_H(g_); } \
    __builtin_amdgcn_s_barrier(); \
    asm volatile("s_waitcnt lgkmcnt(0)" ::: "memory"); \
    __builtin_amdgcn_sched_barrier(0); \
    __builtin_amdgcn_s_setprio(1); \
    _Pragma("unroll") \
    for (int i = 0; i < 4; ++i) { \
        _Pragma("unroll") \
        for (int nj = 0; nj < NJ; ++nj) \
            acc[mh_ * 4 + i][nj] = __builtin_amdgcn_mfma_f32_16x16x32_bf16( \
                aq[i], bq[nj], acc[mh_ * 4 + i][nj], 0, 0, 0); \
    } \
    __builtin_amdgcn_s_setprio(0); \
    if ((ph) == 4 || (ph) == 8) WAITVMC(); \
    __builtin_amdgcn_s_barrier(); \
} while (0)

    // prologue: stage halves 1..6; ensure tile 1 (halves 1-4) complete
    STAGE_H(1); STAGE_H(2); STAGE_H(3); STAGE_H(4); STAGE_H(5); STAGE_H(6);
    WAITVMC();
    __builtin_amdgcn_s_barrier();

    for (int kt2 = 0; kt2 < NTILES / 2; ++kt2) {
        PHASE(1, kt2); PHASE(2, kt2); PHASE(3, kt2); PHASE(4, kt2);
        PHASE(5, kt2); PHASE(6, kt2); PHASE(7, kt2); PHASE(8, kt2);
    }

    // epilogue: C/D layout col = lane&15, row = (lane>>4)*4 + r
    const int er0 = m0 + wr * 128 + (l >> 4) * 4;
    const int ec0 = n0 + wc * WN + lm;
#pragma unroll
    for (int mi = 0; mi < 8; ++mi)
#pragma unroll
        for (int nj = 0; nj < NJ; ++nj)
#pragma unroll
            for (int r = 0; r < 4; ++r)
                C[(size_t)(er0 + mi * 16 + r) * ldc + ec0 + nj * 16] =
                    (_Float16)acc[mi][nj][r];
#undef PHASE
#undef STAGE_H
#undef WAITVMC
#undef ROFF
}

// ===========================================================================
// 128x128 GEMM, BK=64, static two-buffer 2-phase, swizzled LDS.
// BIAS_MODE: 0 none, 1 bias[col], 2 bias[row]. OUT_MODE: 0 f32, 1 bf16.
// ===========================================================================
template<int BIAS_MODE, int OUT_MODE>
__global__ __launch_bounds__(256)
void gemm128(const ushort* __restrict__ A, int lda,
             const ushort* __restrict__ B, int ldb,
             const float* __restrict__ bias,
             void* __restrict__ Cout, int ldc,
             int K, float scale, int nbx)
{
    __shared__ ushort lds_u[32768];
    char* lb = (char*)lds_u;

    const int nwg = gridDim.x;
    const int wg  = blockIdx.x;
    const int logical = (wg & 7) * (nwg >> 3) + (wg >> 3);
    const int bx = logical % nbx, by = logical / nbx;
    const int m0 = by * 128, n0 = bx * 128;

    const int tid = threadIdx.x;
    const int w = tid >> 6, l = tid & 63;
    const int wm = (w >> 1) * 64, wn = (w & 1) * 64;
    const int lm = l & 15;
    const int khb = (l >> 4) * 16;
    const int swzb = ((lm >> 3) & 1) << 5;
    const int aoff = ((wm + lm) * 64 + khb) ^ swzb;
    const int boff = ((wn + lm) * 64 + khb) ^ swzb;

    int rr[4], cc[4];
#pragma unroll
    for (int i = 0; i < 4; ++i) {
        const int rest = (i & 1) * 4096 + tid * 16;
        const int b = rest ^ (((rest >> 9) & 1) << 5);
        rr[i] = b >> 6; cc[i] = (b & 63) >> 1;
    }

#define STAGE128(t_, buf_) do { \
    const int colt_ = (t_) * 64; \
    _Pragma("unroll") \
    for (int i = 0; i < 4; ++i) { \
        const int ldso_ = (i >> 1) * 8192 + (i & 1) * 4096 + tid * 16; \
        gload16(A + (size_t)(m0 + rr[i]) * lda + colt_ + (i >> 1) * 32 + cc[i], \
                lb + (buf_) * 32768 + ldso_); \
        gload16(B + (size_t)(n0 + rr[i]) * ldb + colt_ + (i >> 1) * 32 + cc[i], \
                lb + (buf_) * 32768 + 16384 + ldso_); \
    } \
} while (0)

    f32x4 acc[4][4] = {};

#define COMPUTE128(buf_) do { \
    _Pragma("unroll") \
    for (int kk = 0; kk < 2; ++kk) { \
        s16x8 a_[4], b_[4]; \
        _Pragma("unroll") \
        for (int i = 0; i < 4; ++i) \
            a_[i] = *(const s16x8*)(lb + (buf_) * 32768 + kk * 8192 + aoff + i * 1024); \
        _Pragma("unroll") \
        for (int j = 0; j < 4; ++j) \
            b_[j] = *(const s16x8*)(lb + (buf_) * 32768 + 16384 + kk * 8192 + boff + j * 1024); \
        _Pragma("unroll") \
        for (int i = 0; i < 4; ++i) { \
            _Pragma("unroll") \
            for (int j = 0; j < 4; ++j) \
                acc[i][j] = __builtin_amdgcn_mfma_f32_16x16x32_bf16(a_[i], b_[j], acc[i][j], 0, 0, 0); \
        } \
    } \
} while (0)

    const int NT = K / 64;
    STAGE128(0, 0);
    __syncthreads();
    int t = 0;
    for (; t + 2 < NT; t += 2) {
        STAGE128(t + 1, 1); COMPUTE128(0); __syncthreads();
        STAGE128(t + 2, 0); COMPUTE128(1); __syncthreads();
    }
    STAGE128(NT - 1, 1); COMPUTE128(0); __syncthreads();
    COMPUTE128(1);

    const int r0 = m0 + wm + ((l >> 4) << 2);
    const int c0 = n0 + wn + lm;
#pragma unroll
    for (int i = 0; i < 4; ++i) {
#pragma unroll
        for (int j = 0; j < 4; ++j) {
#pragma unroll
            for (int r = 0; r < 4; ++r) {
                const int row = r0 + i * 16 + r;
                const int col = c0 + j * 16;
                float v = acc[i][j][r];
                if (BIAS_MODE == 1) v += bias[col];
                if (BIAS_MODE == 2) v += bias[row];
                v *= scale;
                if (OUT_MODE == 0) ((float*)Cout)[(size_t)row * ldc + col] = v;
                else               ((ushort*)Cout)[(size_t)row * ldc + col] = f2bf(v);
            }
        }
    }
#undef STAGE128
#undef COMPUTE128
}

// ===========================================================================
// Merged Q+K GEMM: grid 512 (2 blocks/CU). bx<8 -> Q (scale 1/32), else K.
// Same 128x128 2-phase structure as gemm128<1,1>.
// ===========================================================================
__global__ __launch_bounds__(256)
void gemm128_qk(const ushort* __restrict__ Aq,
                const ushort* __restrict__ Wq, const ushort* __restrict__ Wk,
                const float* __restrict__ bqv, const float* __restrict__ bkv,
                ushort* __restrict__ Qo, ushort* __restrict__ Ko)
{
    __shared__ ushort lds_u[32768];
    char* lb = (char*)lds_u;

    const int logical = (blockIdx.x & 7) * 64 + (blockIdx.x >> 3);
    const int bxg = logical & 15, by = logical >> 4;
    const bool isQ = bxg < 8;
    const int bx = isQ ? bxg : bxg - 8;
    const ushort* B = isQ ? Wq : Wk;
    const float* bias = isQ ? bqv : bkv;
    ushort* Cout = isQ ? Qo : Ko;
    const float scale = isQ ? 0.03125f : 1.0f;
    const int m0 = by * 128, n0 = bx * 128;
    const ushort* A = Aq;

    const int tid = threadIdx.x;
    const int w = tid >> 6, l = tid & 63;
    const int wm = (w >> 1) * 64, wn = (w & 1) * 64;
    const int lm = l & 15;
    const int khb = (l >> 4) * 16;
    const int swzb = ((lm >> 3) & 1) << 5;
    const int aoff = ((wm + lm) * 64 + khb) ^ swzb;
    const int boff = ((wn + lm) * 64 + khb) ^ swzb;

    int rr[4], cc[4];
#pragma unroll
    for (int i = 0; i < 4; ++i) {
        const int rest = (i & 1) * 4096 + tid * 16;
        const int b = rest ^ (((rest >> 9) & 1) << 5);
        rr[i] = b >> 6; cc[i] = (b & 63) >> 1;
    }

#define STAGEQK(t_, buf_) do { \
    const int colt_ = (t_) * 64; \
    _Pragma("unroll") \
    for (int i = 0; i < 4; ++i) { \
        const int ldso_ = (i >> 1) * 8192 + (i & 1) * 4096 + tid * 16; \
        gload16(A + (size_t)(m0 + rr[i]) * DM + colt_ + (i >> 1) * 32 + cc[i], \
                lb + (buf_) * 32768 + ldso_); \
        gload16(B + (size_t)(n0 + rr[i]) * DM + colt_ + (i >> 1) * 32 + cc[i], \
                lb + (buf_) * 32768 + 16384 + ldso_); \
    } \
} while (0)

    f32x4 acc[4][4] = {};

#define COMPUTEQK(buf_) do { \
    _Pragma("unroll") \
    for (int kk = 0; kk < 2; ++kk) { \
        s16x8 a_[4], b_[4]; \
        _Pragma("unroll") \
        for (int i = 0; i < 4; ++i) \
            a_[i] = *(const s16x8*)(lb + (buf_) * 32768 + kk * 8192 + aoff + i * 1024); \
        _Pragma("unroll") \
        for (int j = 0; j < 4; ++j) \
            b_[j] = *(const s16x8*)(lb + (buf_) * 32768 + 16384 + kk * 8192 + boff + j * 1024); \
        _Pragma("unroll") \
        for (int i = 0; i < 4; ++i) { \
            _Pragma("unroll") \
            for (int j = 0; j < 4; ++j) \
                acc[i][j] = __builtin_amdgcn_mfma_f32_16x16x32_bf16(a_[i], b_[j], acc[i][j], 0, 0, 0); \
        } \
    } \
} while (0)

    const int NT = DM / 64;
    STAGEQK(0, 0);
    __syncthreads();
    int t = 0;
    for (; t + 2 < NT; t += 2) {
        STAGEQK(t + 1, 1); COMPUTEQK(0); __syncthreads();
        STAGEQK(t + 2, 0); COMPUTEQK(1); __syncthreads();
    }
    STAGEQK(NT - 1, 1); COMPUTEQK(0); __syncthreads();
    COMPUTEQK(1);

    const int r0 = m0 + wm + ((l >> 4) << 2);
    const int c0 = n0 + wn + lm;
#pragma unroll
    for (int i = 0; i < 4; ++i) {
#pragma unroll
        for (int j = 0; j < 4; ++j) {
#pragma unroll
            for (int r = 0; r < 4; ++r) {
                const int row = r0 + i * 16 + r;
                const int col = c0 + j * 16;
                float v = (acc[i][j][r] + bias[col]) * scale;
                Cout[(size_t)row * DM + col] = f2bf(v);
            }
        }
    }
#undef STAGEQK
#undef COMPUTEQK
}

// ---------------------------------------------------------------------------
// Row softmax: S (fp16) -> P (bf16) in-place, fp32 math.
// ---------------------------------------------------------------------------
__global__ __launch_bounds__(256) void softmax_rows(void* __restrict__ Sbase) {
    const int row = blockIdx.x;
    const int tid = threadIdx.x;
    const _Float16* srow = (const _Float16*)Sbase + (size_t)row * SEQ;

    float f[16];
#pragma unroll
    for (int j = 0; j < 2; ++j) {
        h16x8 v = *(const h16x8*)(srow + (size_t)(tid + j * 256) * 8);
#pragma unroll
        for (int e = 0; e < 8; ++e) f[j * 8 + e] = (float)v[e];
    }

    float m = f[0];
#pragma unroll
    for (int i = 1; i < 16; ++i) m = fmaxf(m, f[i]);
#pragma unroll
    for (int off = 32; off > 0; off >>= 1) m = fmaxf(m, __shfl_xor(m, off));

    __shared__ float redm[4], reds[4];
    const int w = tid >> 6, l = tid & 63;
    if (l == 0) redm[w] = m;
    __syncthreads();
    m = fmaxf(fmaxf(redm[0], redm[1]), fmaxf(redm[2], redm[3]));

    float s = 0.f;
#pragma unroll
    for (int i = 0; i < 16; ++i) { f[i] = __expf(f[i] - m); s += f[i]; }
#pragma unroll
    for (int off = 32; off > 0; off >>= 1) s += __shfl_xor(s, off);
    if (l == 0) reds[w] = s;
    __syncthreads();
    s = (reds[0] + reds[1]) + (reds[2] + reds[3]);
    const float inv = 1.0f / s;

    ushort* prow = (ushort*)Sbase + (size_t)row * SEQ;
#pragma unroll
    for (int j = 0; j < 2; ++j) {
        s16x8 o;
#pragma unroll
        for (int e = 0; e < 8; ++e) o[e] = (short)f2bf(f[j * 8 + e] * inv);
        *(s16x8*)(prow + (size_t)(tid + j * 256) * 8) = o;
    }
}

// ---------------------------------------------------------------------------
// split-K reduce: out[j] = p0[j] + p1[j]  (f16 partials -> f32)
// ---------------------------------------------------------------------------
__global__ __launch_bounds__(256)
void reduce2(const _Float16* __restrict__ p0, const _Float16* __restrict__ p1,
             float* __restrict__ out)
{
    const size_t i = (size_t)(blockIdx.x * 256 + threadIdx.x) * 8;
    h16x8 a = *(const h16x8*)(p0 + i);
    h16x8 b = *(const h16x8*)(p1 + i);
    float4 o0, o1;
    o0.x = (float)a[0] + (float)b[0]; o0.y = (float)a[1] + (float)b[1];
    o0.z = (float)a[2] + (float)b[2]; o0.w = (float)a[3] + (float)b[3];
    o1.x = (float)a[4] + (float)b[4]; o1.y = (float)a[5] + (float)b[5];
    o1.z = (float)a[6] + (float)b[6]; o1.w = (float)a[7] + (float)b[7];
    *(float4*)(out + i) = o0;
    *(float4*)(out + i + 4) = o1;
}

// ---------------------------------------------------------------------------
extern "C" void kernel_launch(void* const* d_in, const int* in_sizes, int n_in,
                              void* d_out, int out_size, void* d_ws, size_t ws_size,
                              hipStream_t stream)
{
    const float* x  = (const float*)d_in[0];
    const float* wq = (const float*)d_in[1];
    const float* bq = (const float*)d_in[2];
    const float* wk = (const float*)d_in[3];
    const float* bk = (const float*)d_in[4];
    const float* wv = (const float*)d_in[5];
    const float* bv = (const float*)d_in[6];

    char* ws = (char*)d_ws;
    const size_t MB = 1024 * 1024;
    // layout (56 MB):
    //  [0,8)   Qb bf16 [4096][1024] -> PV partial 0 (f16) after scores
    //  [8,16)  Kb bf16              -> PV partial 1 (f16) after scores
    //  [16,24) Vt bf16 [1024][4096]
    //  [24,56) S  f16  [4096][4096] -> P bf16 in-place
    //  [24,32) xb bf16 (dead before S written); [32,38) weights bf16 (dead)
    ushort*   Qb  = (ushort*)(ws);
    ushort*   Kb  = (ushort*)(ws + 8 * MB);
    ushort*   Vt  = (ushort*)(ws + 16 * MB);
    void*     Sm  = (void*)(ws + 24 * MB);
    ushort*   P   = (ushort*)(ws + 24 * MB);
    ushort*   xb  = (ushort*)(ws + 24 * MB);
    ushort*   wqb = (ushort*)(ws + 32 * MB);
    ushort*   wkb = (ushort*)(ws + 34 * MB);
    ushort*   wvb = (ushort*)(ws + 36 * MB);
    _Float16* Pp  = (_Float16*)(ws);            // partials: ks*4M elems

    // 1) converts (one launch): 1835008 float4s / 256 = 7168 blocks
    cvt_all<<<dim3(7168), dim3(256), 0, stream>>>(x, wq, wk, wv, xb, wqb, wkb, wvb);

    // 2) Q & K merged (grid 512 = 2 blocks/CU)
    gemm128_qk<<<dim3(512), dim3(256), 0, stream>>>(xb, wqb, wkb, bq, bk, Qb, Kb);

    // 3) Vt = wv @ x^T + bv[row] -> V^T [1024][4096]
    gemm128<2, 1><<<dim3(256), dim3(256), 0, stream>>>(
        wvb, DM, xb, DM, bv, Vt, SEQ, DM, 1.0f, 32);

    // 4) scores: S = Qs @ K^T (f16), 8-phase 256^2
    gemm256p<0><<<dim3(256), dim3(512), 0, stream>>>(Qb, Kb, (_Float16*)Sm, DM, SEQ);

    // 5) softmax rows (in-place f16 -> bf16)
    softmax_rows<<<dim3(SEQ), dim3(256), 0, stream>>>(Sm);

    // 6) PV split-K=2, 8-phase 256x128 -> f16 partials in [0,16) MB
    gemm256p<1><<<dim3(256), dim3(512), 0, stream>>>(P, Vt, Pp, SEQ, DM);

    // 7) reduce partials -> f32 d_out
    reduce2<<<dim3(2048), dim3(256), 0, stream>>>(Pp, Pp + (size_t)4096 * 1024,
                                                  (float*)d_out);
}

// Round 9
// 135.112 us; speedup vs baseline: 1.8801x; 1.0508x over previous
//
#include <hip/hip_runtime.h>
#include <hip/hip_bf16.h>
#include <stdint.h>

#define SEQ 4096
#define DM  1024

typedef __attribute__((ext_vector_type(8))) short  s16x8;
typedef __attribute__((ext_vector_type(8))) _Float16 h16x8;
typedef __attribute__((ext_vector_type(4))) float  f32x4;

__device__ __forceinline__ ushort f2bf(float f) {
    union { float f; uint32_t u; } x; x.f = f;
    uint32_t r = x.u + 0x7fffu + ((x.u >> 16) & 1u);
    return (ushort)(r >> 16);
}

__device__ __forceinline__ void gload16(const void* g, void* l) {
    __builtin_amdgcn_global_load_lds(
        (const __attribute__((address_space(1))) void*)g,
        (__attribute__((address_space(3))) void*)l,
        16, 0, 0);
}

// ---------------------------------------------------------------------------
// fused fp32->bf16 convert of x + wq + wk + wv (one launch)
// ---------------------------------------------------------------------------
__global__ __launch_bounds__(256)
void cvt_all(const float* __restrict__ x,  const float* __restrict__ wq,
             const float* __restrict__ wk, const float* __restrict__ wv,
             ushort* __restrict__ xb,  ushort* __restrict__ wqb,
             ushort* __restrict__ wkb, ushort* __restrict__ wvb)
{
    int i = blockIdx.x * 256 + threadIdx.x;      // grid sized exactly (7168*256)
    const float* src; ushort* dst; int k;
    if (i < 1048576) { src = x; dst = xb; k = i; }
    else {
        int j = i - 1048576; int w = j >> 18; k = j & 262143;
        src = (w == 0) ? wq : (w == 1) ? wk : wv;
        dst = (w == 0) ? wqb : (w == 1) ? wkb : wvb;
    }
    float4 v = ((const float4*)src)[k];
    ushort4 o;
    o.x = f2bf(v.x); o.y = f2bf(v.y); o.z = f2bf(v.z); o.w = f2bf(v.w);
    ((ushort4*)dst)[k] = o;
}

// ===========================================================================
// 8-phase 256-row GEMM template (C = A[M,K] * B[N,K]^T, bf16 in).
// MODE 0: scores — BN=256, LDA=1024, 16 K-tiles, grid 256, f16 out.
// MODE 1: PV split-K=2 — BN=128, LDA=4096, 32 K-tiles/slice, grid 256,
//         f16 partials; phases MERGED pairwise (16 MFMA per barrier-pair).
// MODE 2: fused QKV — BN=256, LDA=1024, grid 192 (64 Q + 64 K + 64 Vt tiles),
//         bf16 out with bias (col for Q/K, row for Vt) and Q scale 1/32.
// Schedule: stage half p+6 at sub-phase p; counted vmcnt at tile boundaries
// (4 for BN=256, 3 for BN=128); LAST kt2 iteration peeled with vmcnt(0)
// (fixes tail race where the stage-guard skips loads and the counted wait
// no longer covers the halves the final phases read). st_16x32 XOR swizzle
// both-sides; setprio around MFMA; sched_barrier after lgkmcnt (rule #18).
// ===========================================================================
template<int MODE>
__global__ __launch_bounds__(512, 1)
void gemm256p(const ushort* __restrict__ pA,  const ushort* __restrict__ pB,  void* __restrict__ pC,
              const ushort* __restrict__ pA2, const ushort* __restrict__ pB2, void* __restrict__ pC2,
              const ushort* __restrict__ pA3, const ushort* __restrict__ pB3, void* __restrict__ pC3,
              const float* __restrict__ pb1,  const float* __restrict__ pb2,  const float* __restrict__ pb3)
{
    constexpr int BN      = (MODE == 1) ? 128 : 256;
    constexpr int WN      = BN / 4;
    constexpr int NJ      = BN / 64;
    constexpr int LDA     = (MODE == 1) ? 4096 : 1024;
    constexpr int REG_A   = 16384;               // A half-tile bytes [256][32]
    constexpr int REG_B   = BN * 64;             // B half-tile bytes [BN][32]
    constexpr int BUFSZ   = 2 * (REG_A + REG_B);
    constexpr int NTILES  = (MODE == 1) ? 32 : 16;
    constexpr int TOTAL_H = NTILES * 4;
    constexpr int NWG     = (MODE == 2) ? 192 : 256;

    __shared__ alignas(16) char lb[2 * BUFSZ];

    const int wg = blockIdx.x;
    const int logical = (wg & 7) * (NWG / 8) + (wg >> 3);

    int m0, n0, ldc_ = 0, biasRow = 0;
    const ushort *Ab, *Bb;
    char* Cc;
    const float* bias = nullptr;
    float scale = 1.0f;

    if constexpr (MODE == 0) {
        const int bx = logical & 15, by = logical >> 4;
        m0 = by * 256; n0 = bx * 256;
        Ab = pA + (size_t)m0 * LDA; Bb = pB + (size_t)n0 * LDA;
        Cc = (char*)pC; ldc_ = 4096;
    } else if constexpr (MODE == 1) {
        const int t = logical >> 1, ks = logical & 1;
        m0 = (t >> 3) * 256; n0 = (t & 7) * 128;
        Ab = pA + (size_t)m0 * LDA + ks * 2048;
        Bb = pB + (size_t)n0 * LDA + ks * 2048;
        Cc = (char*)pC + (size_t)ks * 8388608u;  // 4096*1024 f16 elems
        ldc_ = 1024;
    } else {
        const int which = logical / 64, t = logical % 64;
        if (which == 0)      { m0 = (t >> 2) * 256; n0 = (t & 3) * 256;  Ab = pA;  Bb = pB;  Cc = (char*)pC;  bias = pb1; scale = 0.03125f; ldc_ = 1024; }
        else if (which == 1) { m0 = (t >> 2) * 256; n0 = (t & 3) * 256;  Ab = pA2; Bb = pB2; Cc = (char*)pC2; bias = pb2; ldc_ = 1024; }
        else                 { m0 = (t >> 4) * 256; n0 = (t & 15) * 256; Ab = pA3; Bb = pB3; Cc = (char*)pC3; bias = pb3; biasRow = 1; ldc_ = 4096; }
        Ab += (size_t)m0 * LDA; Bb += (size_t)n0 * LDA;
    }

    const int tid = threadIdx.x;
    const int w = tid >> 6, l = tid & 63;
    const int wr = w >> 2, wc = w & 3;
    const int lm = l & 15;
    const int khb = (l >> 4) * 16;

    // staging decode: LDS linear dst, pre-swizzled global src (bit5 ^= bit9)
    const int in0 = tid * 16, in1 = 8192 + tid * 16;
    const int b0 = in0 ^ (((in0 >> 9) & 1) << 5);
    const int b1 = in1 ^ (((in1 >> 9) & 1) << 5);
    const int r0_ = b0 >> 6, c0_ = (b0 & 63) >> 1;
    const int r1_ = b1 >> 6, c1_ = (b1 & 63) >> 1;

    // ds-read bases; swizzle bit depends only on lm bit3
    const int swzb = ((lm >> 3) & 1) << 5;
    const int aoff = (((wr * 128 + lm) * 64 + khb) ^ swzb);
    const int boff = (((wc * WN + lm) * 64 + khb) ^ swzb);

    f32x4 acc[8][NJ] = {};
    s16x8 bqr[NJ];

    // region byte offsets within a buffer: A0, B0, A1, B1
    constexpr int AR0 = 0, BR0 = REG_A, AR1 = REG_A + REG_B, BR1 = 2 * REG_A + REG_B;

#define ROFFX(reg_) ((reg_) == 0 ? AR0 : (reg_) == 1 ? BR0 : (reg_) == 2 ? AR1 : BR1)

#define STAGE_H(g) do { \
    const int hidx_ = (g) - 1, tile_ = hidx_ >> 2, reg_ = hidx_ & 3; \
    const int colb_ = tile_ * 64 + (reg_ >> 1) * 32; \
    char* dst_ = lb + (tile_ & 1) * BUFSZ + ROFFX(reg_); \
    if (reg_ & 1) { \
        gload16(Bb + (size_t)r0_ * LDA + colb_ + c0_, dst_ + in0); \
        if (BN == 256) gload16(Bb + (size_t)r1_ * LDA + colb_ + c1_, dst_ + in1); \
    } else { \
        gload16(Ab + (size_t)r0_ * LDA + colb_ + c0_, dst_ + in0); \
        gload16(Ab + (size_t)r1_ * LDA + colb_ + c1_, dst_ + in1); \
    } \
} while (0)

// 8-sub-phase schedule (BN=256 modes): 16 MFMA per barrier-pair.
#define PHASE8(ph, kt2, VC) do { \
    constexpr int kk_ = (((ph) - 1) >> 1) & 1; \
    constexpr int mh_ = ((ph) - 1) & 1; \
    constexpr int rbuf_ = ((ph) <= 4) ? 0 : 1; \
    constexpr int aro_ = kk_ ? AR1 : AR0; \
    constexpr int bro_ = kk_ ? BR1 : BR0; \
    s16x8 aq[4]; \
    if (mh_ == 0) { \
        _Pragma("unroll") \
        for (int nj = 0; nj < NJ; ++nj) \
            bqr[nj] = *(const s16x8*)(lb + rbuf_ * BUFSZ + bro_ + boff + nj * 1024); \
    } \
    _Pragma("unroll") \
    for (int i = 0; i < 4; ++i) \
        aq[i] = *(const s16x8*)(lb + rbuf_ * BUFSZ + aro_ + aoff + (mh_ * 4 + i) * 1024); \
    { const int g_ = (kt2) * 8 + (ph) + 6; if (g_ <= TOTAL_H) STAGE_H(g_); } \
    __builtin_amdgcn_s_barrier(); \
    asm volatile("s_waitcnt lgkmcnt(0)" ::: "memory"); \
    __builtin_amdgcn_sched_barrier(0); \
    __builtin_amdgcn_s_setprio(1); \
    _Pragma("unroll") \
    for (int i = 0; i < 4; ++i) { \
        _Pragma("unroll") \
        for (int nj = 0; nj < NJ; ++nj) \
            acc[mh_ * 4 + i][nj] = __builtin_amdgcn_mfma_f32_16x16x32_bf16( \
                aq[i], bqr[nj], acc[mh_ * 4 + i][nj], 0, 0, 0); \
    } \
    __builtin_amdgcn_s_setprio(0); \
    if ((ph) == 4 || (ph) == 8) asm volatile("s_waitcnt vmcnt(" #VC ")" ::: "memory"); \
    __builtin_amdgcn_s_barrier(); \
} while (0)

// merged schedule (BN=128 / MODE 1): 4 phases per kt2, 16 MFMA per pair.
// q covers old sub-phases (2q-1, 2q): stage 2 halves, read 8 A + 2 B frags.
#define MPHASE(q, kt2, VC) do { \
    constexpr int kk_ = ((q) - 1) & 1; \
    constexpr int rbuf_ = ((q) <= 2) ? 0 : 1; \
    constexpr int aro_ = kk_ ? AR1 : AR0; \
    constexpr int bro_ = kk_ ? BR1 : BR0; \
    s16x8 aq[8]; \
    _Pragma("unroll") \
    for (int nj = 0; nj < NJ; ++nj) \
        bqr[nj] = *(const s16x8*)(lb + rbuf_ * BUFSZ + bro_ + boff + nj * 1024); \
    _Pragma("unroll") \
    for (int i = 0; i < 8; ++i) \
        aq[i] = *(const s16x8*)(lb + rbuf_ * BUFSZ + aro_ + aoff + i * 1024); \
    { const int g1_ = (kt2) * 8 + 2 * (q) + 5; if (g1_ <= TOTAL_H) STAGE_H(g1_); \
      const int g2_ = g1_ + 1;                 if (g2_ <= TOTAL_H) STAGE_H(g2_); } \
    __builtin_amdgcn_s_barrier(); \
    asm volatile("s_waitcnt lgkmcnt(0)" ::: "memory"); \
    __builtin_amdgcn_sched_barrier(0); \
    __builtin_amdgcn_s_setprio(1); \
    _Pragma("unroll") \
    for (int i = 0; i < 8; ++i) { \
        _Pragma("unroll") \
        for (int nj = 0; nj < NJ; ++nj) \
            acc[i][nj] = __builtin_amdgcn_mfma_f32_16x16x32_bf16( \
                aq[i], bqr[nj], acc[i][nj], 0, 0, 0); \
    } \
    __builtin_amdgcn_s_setprio(0); \
    if ((q) == 2 || (q) == 4) asm volatile("s_waitcnt vmcnt(" #VC ")" ::: "memory"); \
    __builtin_amdgcn_s_barrier(); \
} while (0)

    // prologue: stage halves 1..6; ensure tile 1 (halves 1-4) complete
    STAGE_H(1); STAGE_H(2); STAGE_H(3); STAGE_H(4); STAGE_H(5); STAGE_H(6);
    if constexpr (MODE == 1) asm volatile("s_waitcnt vmcnt(3)" ::: "memory");
    else                     asm volatile("s_waitcnt vmcnt(4)" ::: "memory");
    __builtin_amdgcn_s_barrier();

    if constexpr (MODE == 1) {
        for (int kt2 = 0; kt2 < NTILES / 2 - 1; ++kt2) {
            MPHASE(1, kt2, 3); MPHASE(2, kt2, 3); MPHASE(3, kt2, 3); MPHASE(4, kt2, 3);
        }
        { const int kt2 = NTILES / 2 - 1;
          MPHASE(1, kt2, 0); MPHASE(2, kt2, 0); MPHASE(3, kt2, 0); MPHASE(4, kt2, 0); }
    } else {
        for (int kt2 = 0; kt2 < NTILES / 2 - 1; ++kt2) {
            PHASE8(1, kt2, 4); PHASE8(2, kt2, 4); PHASE8(3, kt2, 4); PHASE8(4, kt2, 4);
            PHASE8(5, kt2, 4); PHASE8(6, kt2, 4); PHASE8(7, kt2, 4); PHASE8(8, kt2, 4);
        }
        { const int kt2 = NTILES / 2 - 1;
          PHASE8(1, kt2, 0); PHASE8(2, kt2, 0); PHASE8(3, kt2, 0); PHASE8(4, kt2, 0);
          PHASE8(5, kt2, 0); PHASE8(6, kt2, 0); PHASE8(7, kt2, 0); PHASE8(8, kt2, 0); }
    }

    // epilogue: C/D layout col = lane&15, row = (lane>>4)*4 + r
    const int er0 = m0 + wr * 128 + (l >> 4) * 4;
    const int ec0 = n0 + wc * WN + lm;
#pragma unroll
    for (int mi = 0; mi < 8; ++mi) {
#pragma unroll
        for (int nj = 0; nj < NJ; ++nj) {
#pragma unroll
            for (int r = 0; r < 4; ++r) {
                const int row = er0 + mi * 16 + r;
                const int col = ec0 + nj * 16;
                if constexpr (MODE == 2) {
                    const float v = (acc[mi][nj][r] + bias[biasRow ? row : col]) * scale;
                    ((ushort*)Cc)[(size_t)row * ldc_ + col] = f2bf(v);
                } else {
                    ((_Float16*)Cc)[(size_t)row * ldc_ + col] = (_Float16)acc[mi][nj][r];
                }
            }
        }
    }
#undef MPHASE
#undef PHASE8
#undef STAGE_H
#undef ROFFX
}

// ---------------------------------------------------------------------------
// Row softmax: S (fp16) -> P (bf16) in-place, fp32 math.
// ---------------------------------------------------------------------------
__global__ __launch_bounds__(256) void softmax_rows(void* __restrict__ Sbase) {
    const int row = blockIdx.x;
    const int tid = threadIdx.x;
    const _Float16* srow = (const _Float16*)Sbase + (size_t)row * SEQ;

    float f[16];
#pragma unroll
    for (int j = 0; j < 2; ++j) {
        h16x8 v = *(const h16x8*)(srow + (size_t)(tid + j * 256) * 8);
#pragma unroll
        for (int e = 0; e < 8; ++e) f[j * 8 + e] = (float)v[e];
    }

    float m = f[0];
#pragma unroll
    for (int i = 1; i < 16; ++i) m = fmaxf(m, f[i]);
#pragma unroll
    for (int off = 32; off > 0; off >>= 1) m = fmaxf(m, __shfl_xor(m, off));

    __shared__ float redm[4], reds[4];
    const int w = tid >> 6, l = tid & 63;
    if (l == 0) redm[w] = m;
    __syncthreads();
    m = fmaxf(fmaxf(redm[0], redm[1]), fmaxf(redm[2], redm[3]));

    float s = 0.f;
#pragma unroll
    for (int i = 0; i < 16; ++i) { f[i] = __expf(f[i] - m); s += f[i]; }
#pragma unroll
    for (int off = 32; off > 0; off >>= 1) s += __shfl_xor(s, off);
    if (l == 0) reds[w] = s;
    __syncthreads();
    s = (reds[0] + reds[1]) + (reds[2] + reds[3]);
    const float inv = 1.0f / s;

    ushort* prow = (ushort*)Sbase + (size_t)row * SEQ;
#pragma unroll
    for (int j = 0; j < 2; ++j) {
        s16x8 o;
#pragma unroll
        for (int e = 0; e < 8; ++e) o[e] = (short)f2bf(f[j * 8 + e] * inv);
        *(s16x8*)(prow + (size_t)(tid + j * 256) * 8) = o;
    }
}

// ---------------------------------------------------------------------------
// split-K reduce: out[j] = p0[j] + p1[j]  (f16 partials -> f32)
// ---------------------------------------------------------------------------
__global__ __launch_bounds__(256)
void reduce2(const _Float16* __restrict__ p0, const _Float16* __restrict__ p1,
             float* __restrict__ out)
{
    const size_t i = (size_t)(blockIdx.x * 256 + threadIdx.x) * 8;
    h16x8 a = *(const h16x8*)(p0 + i);
    h16x8 b = *(const h16x8*)(p1 + i);
    float4 o0, o1;
    o0.x = (float)a[0] + (float)b[0]; o0.y = (float)a[1] + (float)b[1];
    o0.z = (float)a[2] + (float)b[2]; o0.w = (float)a[3] + (float)b[3];
    o1.x = (float)a[4] + (float)b[4]; o1.y = (float)a[5] + (float)b[5];
    o1.z = (float)a[6] + (float)b[6]; o1.w = (float)a[7] + (float)b[7];
    *(float4*)(out + i) = o0;
    *(float4*)(out + i + 4) = o1;
}

// ---------------------------------------------------------------------------
extern "C" void kernel_launch(void* const* d_in, const int* in_sizes, int n_in,
                              void* d_out, int out_size, void* d_ws, size_t ws_size,
                              hipStream_t stream)
{
    const float* x  = (const float*)d_in[0];
    const float* wq = (const float*)d_in[1];
    const float* bq = (const float*)d_in[2];
    const float* wk = (const float*)d_in[3];
    const float* bk = (const float*)d_in[4];
    const float* wv = (const float*)d_in[5];
    const float* bv = (const float*)d_in[6];

    char* ws = (char*)d_ws;
    const size_t MB = 1024 * 1024;
    // layout (56 MB):
    //  [0,8)   Qb bf16 [4096][1024] -> PV partial 0 (f16) after scores
    //  [8,16)  Kb bf16              -> PV partial 1 (f16) after scores
    //  [16,24) Vt bf16 [1024][4096]
    //  [24,56) S  f16  [4096][4096] -> P bf16 in-place
    //  [24,32) xb bf16 (dead before S written); [32,38) weights bf16 (dead)
    ushort*   Qb  = (ushort*)(ws);
    ushort*   Kb  = (ushort*)(ws + 8 * MB);
    ushort*   Vt  = (ushort*)(ws + 16 * MB);
    void*     Sm  = (void*)(ws + 24 * MB);
    ushort*   P   = (ushort*)(ws + 24 * MB);
    ushort*   xb  = (ushort*)(ws + 24 * MB);
    ushort*   wqb = (ushort*)(ws + 32 * MB);
    ushort*   wkb = (ushort*)(ws + 34 * MB);
    ushort*   wvb = (ushort*)(ws + 36 * MB);
    _Float16* Pp  = (_Float16*)(ws);            // partials: ks * 4M f16 elems

    // 1) converts (one launch)
    cvt_all<<<dim3(7168), dim3(256), 0, stream>>>(x, wq, wk, wv, xb, wqb, wkb, wvb);

    // 2) fused QKV: Q=(x wq^T + bq)/32, K=x wk^T + bk, Vt=wv x^T + bv[row]
    gemm256p<2><<<dim3(192), dim3(512), 0, stream>>>(
        xb, wqb, Qb, xb, wkb, Kb, wvb, xb, Vt, bq, bk, bv);

    // 3) scores: S = Qs @ K^T (f16), 8-phase 256^2
    gemm256p<0><<<dim3(256), dim3(512), 0, stream>>>(
        Qb, Kb, Sm, nullptr, nullptr, nullptr, nullptr, nullptr, nullptr,
        nullptr, nullptr, nullptr);

    // 4) softmax rows (in-place f16 -> bf16)
    softmax_rows<<<dim3(SEQ), dim3(256), 0, stream>>>(Sm);

    // 5) PV split-K=2, merged-phase 256x128 -> f16 partials in [0,16) MB
    gemm256p<1><<<dim3(256), dim3(512), 0, stream>>>(
        P, Vt, Pp, nullptr, nullptr, nullptr, nullptr, nullptr, nullptr,
        nullptr, nullptr, nullptr);

    // 6) reduce partials -> f32 d_out
    reduce2<<<dim3(2048), dim3(256), 0, stream>>>(Pp, Pp + (size_t)4096 * 1024,
                                                  (float*)d_out);
}